// Round 11
// baseline (203.813 us; speedup 1.0000x reference)
//
#include <hip/hip_runtime.h>
#include <math.h>

#define HIDDEN 1024
#define NF4 256          // float4 per row
#define NEXP 64
#define ROWS 32
#define TOPK 4
#define INNER 8
#define TOTAL 8
#define TB 2             // tokens per block, phase 1 (512 blocks -> 2/CU)
#define G 4              // pairs per block, phase 2 (~1024 workers -> 4/CU)
#define MAXCH 40         // cap 160 pairs/expert
#define REP 4            // probe: internal repeat factor

__device__ __forceinline__ float dot4(float4 a, float4 b) {
    return a.x * b.x + a.y * b.y + a.z * b.z + a.w * b.w;
}

// ---------------- phase 1: router + scatter (+ zero done[]) ----------------
__global__ __launch_bounds__(256) void p1_router(
    const float* __restrict__ x, const float* __restrict__ rw,
    int* __restrict__ count, int* __restrict__ tok_list,
    float* __restrict__ w_arr, int* __restrict__ done)
{
    __shared__ float4 sx[TB * NF4];      // 8 KB
    __shared__ float  red[TB][NEXP];

    const int t = threadIdx.x;
    const int g = t >> 4, j = t & 15;
    const int tok0 = blockIdx.x * TB;

    if (t < TB) done[tok0 + t] = 0;      // zero completion counters for p2

    {   // stage TB x rows, coalesced 16 B/lane
        const float4* xs = (const float4*)(x + (size_t)tok0 * HIDDEN);
        #pragma unroll
        for (int i = 0; i < TB; ++i) sx[i * NF4 + t] = xs[i * NF4 + t];
    }
    __syncthreads();

    const float4* wp[4];
    #pragma unroll
    for (int m = 0; m < 4; ++m)
        wp[m] = (const float4*)(rw + (size_t)(g + 16 * m) * HIDDEN);

    float acc[4][TB];
    #pragma unroll
    for (int m = 0; m < 4; ++m)
        #pragma unroll
        for (int tk = 0; tk < TB; ++tk) acc[m][tk] = 0.f;

    #pragma unroll 2
    for (int k = 0; k < 16; ++k) {
        const int c = j + 16 * k;
        float4 wf[4];
        #pragma unroll
        for (int m = 0; m < 4; ++m) wf[m] = wp[m][c];
        #pragma unroll
        for (int tk = 0; tk < TB; ++tk) {
            float4 xb = sx[tk * NF4 + c];
            #pragma unroll
            for (int m = 0; m < 4; ++m) acc[m][tk] += dot4(wf[m], xb);
        }
    }

    #pragma unroll
    for (int m = 0; m < 4; ++m)
        #pragma unroll
        for (int tk = 0; tk < TB; ++tk) {
            float v = acc[m][tk];
            v += __shfl_xor(v, 1); v += __shfl_xor(v, 2);
            v += __shfl_xor(v, 4); v += __shfl_xor(v, 8);
            acc[m][tk] = v;
        }
    if (j == 0)
        #pragma unroll
        for (int m = 0; m < 4; ++m)
            #pragma unroll
            for (int tk = 0; tk < TB; ++tk)
                red[tk][g + 16 * m] = acc[m][tk];
    __syncthreads();

    if (t < TB) {
        const int token = tok0 + t;
        float vals[TOPK]; int sel[TOPK];
        for (int k = 0; k < TOPK; ++k) {
            float best = -INFINITY; int bi = 0;
            for (int e = 0; e < NEXP; ++e) {
                float v = red[t][e];
                if (v > best) { best = v; bi = e; }   // ties -> lowest index
            }
            red[t][bi] = -INFINITY;
            sel[k] = bi; vals[k] = best;
        }
        const float m = vals[0];
        float ex[TOPK], s = 0.f;
        for (int k = 0; k < TOPK; ++k) { ex[k] = expf(vals[k] - m); s += ex[k]; }
        const float inv = 1.f / s;
        for (int k = 0; k < TOPK; ++k) {
            w_arr[token * TOPK + k] = ex[k] * inv;
            int pos = atomicAdd(&count[sel[k]], 1);
            tok_list[sel[k] * 1024 + pos] = (token << 2) | k;
        }
    }
}

// ---------------- phase 2: expert matmuls + inner top-k + finisher ----------
__global__ __launch_bounds__(256) void p2_experts(
    const float* __restrict__ x,
    const float* __restrict__ wg, const float* __restrict__ wu,
    const int* __restrict__ count, const int* __restrict__ tok_list,
    int* __restrict__ ids_buf, int* __restrict__ done,
    const float* __restrict__ w_arr, float* __restrict__ out, int bs)
{
    __shared__ float4 sx[G * NF4];           // 16 KB
    __shared__ float  sred[G][NEXP];
    __shared__ float  sscore[G][ROWS];
    __shared__ int    s_entry[G];

    const int e = blockIdx.x, c0 = blockIdx.y;
    const int n = count[e];
    const int i0 = c0 * G;
    if (i0 >= n) return;
    const int T = (n - i0 < G) ? (n - i0) : G;

    const int t = threadIdx.x;
    const int g = t >> 4, j = t & 15;

    if (t < G)
        s_entry[t] = tok_list[e * 1024 + i0 + ((t < T) ? t : 0)];
    __syncthreads();

    {   // stage G token rows, coalesced
        #pragma unroll
        for (int i = 0; i < G; ++i)
            sx[i * NF4 + t] =
                ((const float4*)(x + (size_t)(s_entry[i] >> 2) * HIDDEN))[t];
    }
    __syncthreads();

    const float4* wp[4];
    #pragma unroll
    for (int m = 0; m < 4; ++m) {
        const int R = g + 16 * m;
        wp[m] = (const float4*)((R < ROWS)
            ? wg + ((size_t)e * ROWS + R) * HIDDEN
            : wu + ((size_t)e * ROWS + (R - ROWS)) * HIDDEN);
    }

    float acc[4][G];
    #pragma unroll
    for (int m = 0; m < 4; ++m)
        #pragma unroll
        for (int tk = 0; tk < G; ++tk) acc[m][tk] = 0.f;

    #pragma unroll 2
    for (int k = 0; k < 16; ++k) {
        const int c = j + 16 * k;
        float4 wf[4];
        #pragma unroll
        for (int m = 0; m < 4; ++m) wf[m] = wp[m][c];
        #pragma unroll
        for (int tk = 0; tk < G; ++tk) {
            float4 xb = sx[tk * NF4 + c];
            #pragma unroll
            for (int m = 0; m < 4; ++m) acc[m][tk] += dot4(wf[m], xb);
        }
    }

    #pragma unroll
    for (int m = 0; m < 4; ++m)
        #pragma unroll
        for (int tk = 0; tk < G; ++tk) {
            float v = acc[m][tk];
            v += __shfl_xor(v, 1); v += __shfl_xor(v, 2);
            v += __shfl_xor(v, 4); v += __shfl_xor(v, 8);
            acc[m][tk] = v;
        }
    if (j == 0)
        #pragma unroll
        for (int m = 0; m < 4; ++m)
            #pragma unroll
            for (int tk = 0; tk < G; ++tk)
                sred[tk][g + 16 * m] = acc[m][tk];
    __syncthreads();

    if (t < 32 * G) {
        const int tok = t >> 5, rr = t & 31;
        const float gg = sred[tok][rr], uu = sred[tok][rr + 32];
        sscore[tok][rr] = fabsf(uu * (gg / (1.f + expf(-gg))));
    }
    __syncthreads();

    if (t < T) {
        const int entry = s_entry[t], token = entry >> 2, slot = entry & 3;
        float inner[INNER];
        #pragma unroll
        for (int i = 0; i < INNER; ++i)
            inner[i] = 0.25f * (sscore[t][4*i] + sscore[t][4*i+1]
                              + sscore[t][4*i+2] + sscore[t][4*i+3]);
        const int kk  = (slot == 0) ? 3 : ((slot == 3) ? 1 : 2);
        const int off = (slot == 0) ? 0 : ((slot == 1) ? 3 : ((slot == 2) ? 5 : 7));
        for (int k = 0; k < kk; ++k) {
            float best = -INFINITY; int bi = 0;
            #pragma unroll
            for (int i = 0; i < INNER; ++i)
                if (inner[i] > best) { best = inner[i]; bi = i; }
            inner[bi] = -INFINITY;
            atomicExch(&ids_buf[token * TOTAL + off + k], e * INNER + bi);
        }

        const int old = atomicAdd(&done[token], kk);
        if (old + kk == TOTAL) {            // last contributor: finish token
            int ids[TOTAL];
            #pragma unroll
            for (int i = 0; i < TOTAL; ++i)
                ids[i] = atomicOr(&ids_buf[token * TOTAL + i], 0);
            for (int i = 1; i < TOTAL; ++i) {        // insertion sort, descending
                int v = ids[i]; int jj = i - 1;
                while (jj >= 0 && ids[jj] < v) { ids[jj+1] = ids[jj]; --jj; }
                ids[jj+1] = v;
            }
            const float w0 = w_arr[token*4+0], w1 = w_arr[token*4+1];
            const float w2 = w_arr[token*4+2], w3 = w_arr[token*4+3];
            const float ws[TOTAL] = {w0, w0, w0, w1, w1, w2, w2, w3};

            float* oid = out + (size_t)token * TOTAL;
            float* ow  = out + (size_t)bs * TOTAL + (size_t)token * TOTAL;
            #pragma unroll
            for (int i = 0; i < TOTAL; ++i) { oid[i] = (float)ids[i]; ow[i] = ws[i]; }
        }
    }
}

// ---------------- p2_probe: DIAGNOSTIC ----------------
// Identical compute to p2_experts, repeated REP times; no done/finisher, no
// output writes -> harmless after the real p2 (atomicExch rewrites identical
// values). Purpose: dur_us delta = REP * p2_true, and if REP*p2 > ~44 us the
// dispatch surfaces in rocprof top-5 with full PMC.
__global__ __launch_bounds__(256) void p2_probe(
    const float* __restrict__ x,
    const float* __restrict__ wg, const float* __restrict__ wu,
    const int* __restrict__ count, const int* __restrict__ tok_list,
    int* __restrict__ ids_buf)
{
    __shared__ float4 sx[G * NF4];
    __shared__ float  sred[G][NEXP];
    __shared__ float  sscore[G][ROWS];
    __shared__ int    s_entry[G];

    const int e = blockIdx.x, c0 = blockIdx.y;
    const int n = count[e];
    const int i0 = c0 * G;
    if (i0 >= n) return;
    const int T = (n - i0 < G) ? (n - i0) : G;

    const int t = threadIdx.x;
    const int g = t >> 4, j = t & 15;

    for (int rep = 0; rep < REP; ++rep) {
        if (t < G)
            s_entry[t] = tok_list[e * 1024 + i0 + ((t < T) ? t : 0)];
        __syncthreads();

        #pragma unroll
        for (int i = 0; i < G; ++i)
            sx[i * NF4 + t] =
                ((const float4*)(x + (size_t)(s_entry[i] >> 2) * HIDDEN))[t];
        __syncthreads();

        const float4* wp[4];
        #pragma unroll
        for (int m = 0; m < 4; ++m) {
            const int R = g + 16 * m;
            wp[m] = (const float4*)((R < ROWS)
                ? wg + ((size_t)e * ROWS + R) * HIDDEN
                : wu + ((size_t)e * ROWS + (R - ROWS)) * HIDDEN);
        }

        float acc[4][G];
        #pragma unroll
        for (int m = 0; m < 4; ++m)
            #pragma unroll
            for (int tk = 0; tk < G; ++tk) acc[m][tk] = 0.f;

        #pragma unroll 2
        for (int k = 0; k < 16; ++k) {
            const int c = j + 16 * k;
            float4 wf[4];
            #pragma unroll
            for (int m = 0; m < 4; ++m) wf[m] = wp[m][c];
            #pragma unroll
            for (int tk = 0; tk < G; ++tk) {
                float4 xb = sx[tk * NF4 + c];
                #pragma unroll
                for (int m = 0; m < 4; ++m) acc[m][tk] += dot4(wf[m], xb);
            }
        }

        #pragma unroll
        for (int m = 0; m < 4; ++m)
            #pragma unroll
            for (int tk = 0; tk < G; ++tk) {
                float v = acc[m][tk];
                v += __shfl_xor(v, 1); v += __shfl_xor(v, 2);
                v += __shfl_xor(v, 4); v += __shfl_xor(v, 8);
                acc[m][tk] = v;
            }
        if (j == 0)
            #pragma unroll
            for (int m = 0; m < 4; ++m)
                #pragma unroll
                for (int tk = 0; tk < G; ++tk)
                    sred[tk][g + 16 * m] = acc[m][tk];
        __syncthreads();

        if (t < 32 * G) {
            const int tok = t >> 5, rr = t & 31;
            const float gg = sred[tok][rr], uu = sred[tok][rr + 32];
            sscore[tok][rr] = fabsf(uu * (gg / (1.f + expf(-gg))));
        }
        __syncthreads();

        if (t < T) {
            const int entry = s_entry[t], token = entry >> 2, slot = entry & 3;
            float inner[INNER];
            #pragma unroll
            for (int i = 0; i < INNER; ++i)
                inner[i] = 0.25f * (sscore[t][4*i] + sscore[t][4*i+1]
                                  + sscore[t][4*i+2] + sscore[t][4*i+3]);
            const int kk  = (slot == 0) ? 3 : ((slot == 3) ? 1 : 2);
            const int off = (slot == 0) ? 0 : ((slot == 1) ? 3 : ((slot == 2) ? 5 : 7));
            for (int k = 0; k < kk; ++k) {
                float best = -INFINITY; int bi = 0;
                #pragma unroll
                for (int i = 0; i < INNER; ++i)
                    if (inner[i] > best) { best = inner[i]; bi = i; }
                inner[bi] = -INFINITY;
                atomicExch(&ids_buf[token * TOTAL + off + k], e * INNER + bi);
            }
        }
        __syncthreads();
    }
}

extern "C" void kernel_launch(void* const* d_in, const int* in_sizes, int n_in,
                              void* d_out, int out_size, void* d_ws, size_t ws_size,
                              hipStream_t stream) {
    const float* x  = (const float*)d_in[0];
    const float* rw = (const float*)d_in[1];
    const float* wg = (const float*)d_in[2];
    const float* wu = (const float*)d_in[3];
    float* out = (float*)d_out;
    const int bs = in_sizes[0] / HIDDEN;   // 1024

    // workspace: count[64] | tok_list[64*1024] | w_arr[bs*4] | ids_buf[bs*8] | done[bs]
    int*   count    = (int*)d_ws;
    int*   tok_list = count + 64;
    float* w_arr    = (float*)(tok_list + 64 * 1024);
    int*   ids_buf  = (int*)(w_arr + (size_t)bs * TOPK);
    int*   done     = ids_buf + (size_t)bs * TOTAL;

    hipMemsetAsync(count, 0, 64 * sizeof(int), stream);
    hipLaunchKernelGGL(p1_router, dim3(bs / TB), dim3(256), 0, stream,
                       x, rw, count, tok_list, w_arr, done);
    hipLaunchKernelGGL(p2_experts, dim3(NEXP, MAXCH), dim3(256), 0, stream,
                       x, wg, wu, count, tok_list, ids_buf, done, w_arr, out, bs);
    // diagnostic: REP x p2 compute, harmless to outputs
    hipLaunchKernelGGL(p2_probe, dim3(NEXP, MAXCH), dim3(256), 0, stream,
                       x, wg, wu, count, tok_list, ids_buf);
}